// Round 7
// baseline (1120.862 us; speedup 1.0000x reference)
//
#include <hip/hip_runtime.h>
#include <hip/hip_cooperative_groups.h>

namespace cg = cooperative_groups;

#define N_NODES 100000
#define N_EDGES 1600000
#define IN_DIM 128
#define HID 64
#define NB 782               // ceil(100000 / 128) buckets of 128 nodes
#define NT64 1563            // ceil(N_NODES / 64) gemm tiles
#define NGROUP 25000         // N_NODES / 4 agg groups
#define MAXGRID 2048

typedef __attribute__((ext_vector_type(8))) _Float16 h8v;
typedef __attribute__((ext_vector_type(4))) float f4v;

struct MegaArgs {
  const float* x; const int* ei;
  const float* Wp; const float* bp;
  const float* W1; const float* b1;
  const float* W2; const float* b2;
  const float* W3; const float* b3;
  float* out;
  float* bufA; _Float16* hw16;
  int* pairs; int* csr; int* offs; float* dinv;
  int* bsz; int* bboff; int* bcur;
  _Float16* WpH; _Float16* WpL; _Float16* W1H; _Float16* W1L;
  _Float16* W2H; _Float16* W2L; _Float16* W3H; _Float16* W3L;
};

union SM {
  int bh[NB];
  struct { int cnt[NB]; int base[NB]; } part;
  struct { int ldeg[128]; int sc[128]; int lcur[128]; } cd;
  int scan[256];
};

__device__ __forceinline__ void d_split(const float* __restrict__ W,
                                        _Float16* __restrict__ hi,
                                        _Float16* __restrict__ lo, int K, int i) {
  int k = i >> 6, n = i & 63;
  float v = W[i];
  _Float16 h = (_Float16)v;
  float r = v - (float)h;
  hi[n * K + k] = h;
  lo[n * K + k] = (_Float16)r;
}

// ---- MFMA GEMM tile: 64 rows x 64 cols; split-fp16, fp32-equivalent accuracy ----
template <int K, bool BIAS, typename OutT>
__device__ __forceinline__ void d_gemm(int tile, const float* __restrict__ X,
                                       const _Float16* __restrict__ Wh,
                                       const _Float16* __restrict__ Wl,
                                       const float* __restrict__ bias,
                                       OutT* __restrict__ out) {
  int wave = threadIdx.x >> 6;
  int lane = threadIdx.x & 63;
  int fi = lane & 15;
  int quad = lane >> 4;
  int r0 = tile * 64 + wave * 16;
  int row_l = r0 + fi;
  if (row_l >= N_NODES) row_l = N_NODES - 1;
  const float* xp = X + (size_t)row_l * K + quad * 8;

  f4v acc[4];
#pragma unroll
  for (int ct = 0; ct < 4; ++ct) acc[ct] = (f4v){0.f, 0.f, 0.f, 0.f};

#pragma unroll
  for (int k0 = 0; k0 < K; k0 += 32) {
    f4v xa = *(const f4v*)(xp + k0);
    f4v xb = *(const f4v*)(xp + k0 + 4);
    h8v ah, al;
#pragma unroll
    for (int j = 0; j < 4; ++j) {
      _Float16 h = (_Float16)xa[j];
      ah[j] = h;
      al[j] = (_Float16)(xa[j] - (float)h);
    }
#pragma unroll
    for (int j = 0; j < 4; ++j) {
      _Float16 h = (_Float16)xb[j];
      ah[4 + j] = h;
      al[4 + j] = (_Float16)(xb[j] - (float)h);
    }
    const _Float16* whp = Wh + (size_t)fi * K + k0 + quad * 8;
    const _Float16* wlp = Wl + (size_t)fi * K + k0 + quad * 8;
#pragma unroll
    for (int ct = 0; ct < 4; ++ct) {
      h8v bh = *(const h8v*)(whp + (size_t)ct * 16 * K);
      h8v bl = *(const h8v*)(wlp + (size_t)ct * 16 * K);
      acc[ct] = __builtin_amdgcn_mfma_f32_16x16x32_f16(ah, bh, acc[ct], 0, 0, 0);
      acc[ct] = __builtin_amdgcn_mfma_f32_16x16x32_f16(al, bh, acc[ct], 0, 0, 0);
      acc[ct] = __builtin_amdgcn_mfma_f32_16x16x32_f16(ah, bl, acc[ct], 0, 0, 0);
    }
  }
#pragma unroll
  for (int ct = 0; ct < 4; ++ct) {
    float bv = 0.f;
    if (BIAS) bv = bias[ct * 16 + fi];
#pragma unroll
    for (int j = 0; j < 4; ++j) {
      int orow = r0 + quad * 4 + j;
      if (orow < N_NODES) out[(size_t)orow * HID + ct * 16 + fi] = (OutT)(acc[ct][j] + bv);
    }
  }
}

// ---- aggregation: wave per node, oct-parallel, 4-deep (32 gathers in flight) ----
template <int MODE>
__device__ __forceinline__ void d_agg(int grp, const _Float16* __restrict__ hw,
                                      const int* __restrict__ offs,
                                      const int* __restrict__ csr,
                                      const float* __restrict__ dinv,
                                      const float* __restrict__ bias,
                                      float* __restrict__ out) {
  int node = grp * 4 + (threadIdx.x >> 6);
  int lane = threadIdx.x & 63;
  int oct = lane >> 3;
  int fi = lane & 7;
  float di = dinv[node];
  int beg = offs[node];
  int end = offs[node + 1];

  float acc[8];
#pragma unroll
  for (int c = 0; c < 8; ++c) acc[c] = 0.f;

  if (oct == 0) {
    h8v hv = *(const h8v*)(hw + (size_t)node * HID + fi * 8);
    float w = di * di;
#pragma unroll
    for (int c = 0; c < 8; ++c) acc[c] += (float)hv[c] * w;
  }
  for (int e0 = beg + oct; e0 < end; e0 += 32) {
    int ss[4];
    float ww[4];
#pragma unroll
    for (int j = 0; j < 4; ++j) {
      int e = e0 + 8 * j;
      bool v = e < end;
      int s = csr[v ? e : beg];
      ss[j] = v ? s : node;
      ww[j] = v ? di : 0.0f;
    }
#pragma unroll
    for (int j = 0; j < 4; ++j) ww[j] *= dinv[ss[j]];
    h8v hv[4];
#pragma unroll
    for (int j = 0; j < 4; ++j)
      hv[j] = *(const h8v*)(hw + (size_t)ss[j] * HID + fi * 8);
#pragma unroll
    for (int j = 0; j < 4; ++j)
#pragma unroll
      for (int c = 0; c < 8; ++c) acc[c] += (float)hv[j][c] * ww[j];
  }
#pragma unroll
  for (int c = 0; c < 8; ++c) {
    float v = acc[c];
    v += __shfl_xor(v, 8);
    v += __shfl_xor(v, 16);
    v += __shfl_xor(v, 32);
    acc[c] = v;
  }
  if (oct == 0) {
#pragma unroll
    for (int c = 0; c < 8; ++c) acc[c] += bias[fi * 8 + c];
    if (MODE == 0) {
#pragma unroll
      for (int c = 0; c < 8; ++c) acc[c] = fmaxf(acc[c], 0.f);
    } else {
      float ss = 0.f;
#pragma unroll
      for (int c = 0; c < 8; ++c) ss += acc[c] * acc[c];
      ss += __shfl_xor(ss, 1);
      ss += __shfl_xor(ss, 2);
      ss += __shfl_xor(ss, 4);
      float sc = 1.0f / fmaxf(sqrtf(ss), 1e-12f);
#pragma unroll
      for (int c = 0; c < 8; ++c) acc[c] *= sc;
    }
    f4v o0 = {acc[0], acc[1], acc[2], acc[3]};
    f4v o1 = {acc[4], acc[5], acc[6], acc[7]};
    *(f4v*)(out + (size_t)node * HID + fi * 8) = o0;
    *(f4v*)(out + (size_t)node * HID + fi * 8 + 4) = o1;
  }
}

// ============================= the mega kernel =============================
__global__ __launch_bounds__(256, 4) void k_mega(MegaArgs a) {
  cg::grid_group g = cg::this_grid();
  __shared__ SM sm;
  int blk = blockIdx.x;
  int grid = gridDim.x;
  int t = threadIdx.x;

  // ---- P0: zero bsz (block 0) + weight split prep (blocks 1..80) ----
  if (blk == 0) {
    for (int i = t; i < NB; i += 256) a.bsz[i] = 0;
  } else if (blk <= 32) {
    d_split(a.Wp, a.WpH, a.WpL, IN_DIM, (blk - 1) * 256 + t);
  } else if (blk <= 48) {
    d_split(a.W1, a.W1H, a.W1L, HID, (blk - 33) * 256 + t);
  } else if (blk <= 64) {
    d_split(a.W2, a.W2H, a.W2L, HID, (blk - 49) * 256 + t);
  } else if (blk <= 80) {
    d_split(a.W3, a.W3H, a.W3L, HID, (blk - 65) * 256 + t);
  }
  g.sync();

  // ---- P1: bucket histogram (blocks 0..195) || pre-GEMM (blocks 196+) ----
  if (blk < 196) {
    for (int i = t; i < NB; i += 256) sm.bh[i] = 0;
    __syncthreads();
    int e0 = blk * 8192, e1 = min(e0 + 8192, N_EDGES);
    for (int e = e0 + t; e < e1; e += 256)
      atomicAdd(&sm.bh[a.ei[N_EDGES + e] >> 7], 1);
    __syncthreads();
    for (int i = t; i < NB; i += 256)
      if (sm.bh[i]) atomicAdd(&a.bsz[i], sm.bh[i]);
  } else {
    for (int tile = blk - 196; tile < NT64; tile += grid - 196)
      d_gemm<IN_DIM, true, float>(tile, a.x, a.WpH, a.WpL, a.bp, a.bufA);
  }
  g.sync();

  // ---- P2: bucket exclusive scan (block 0; 256 thr x 4 slots) ----
  if (blk == 0) {
    int c[4];
    int idx0 = t * 4;
#pragma unroll
    for (int j = 0; j < 4; ++j) c[j] = (idx0 + j < NB) ? a.bsz[idx0 + j] : 0;
    int tsum = c[0] + c[1] + c[2] + c[3];
    int val = tsum;
    sm.scan[t] = val;
    __syncthreads();
    for (int off = 1; off < 256; off <<= 1) {
      int u = (t >= off) ? sm.scan[t - off] : 0;
      __syncthreads();
      val += u;
      sm.scan[t] = val;
      __syncthreads();
    }
    int excl = val - tsum;
#pragma unroll
    for (int j = 0; j < 4; ++j) {
      int idx = idx0 + j;
      if (idx < NB) { a.bboff[idx] = excl; a.bcur[idx] = excl; }
      excl += c[j];
    }
    if (t == 255) a.bboff[NB] = val;  // == N_EDGES
  }
  g.sync();

  // ---- P3: partition edges into buckets; pack (dlocal<<17 | src) ----
  if (blk < 196) {
    for (int i = t; i < NB; i += 256) sm.part.cnt[i] = 0;
    __syncthreads();
    int e0 = blk * 8192, e1 = min(e0 + 8192, N_EDGES);
    for (int e = e0 + t; e < e1; e += 256)
      atomicAdd(&sm.part.cnt[a.ei[N_EDGES + e] >> 7], 1);
    __syncthreads();
    for (int i = t; i < NB; i += 256) {
      int c = sm.part.cnt[i];
      sm.part.base[i] = c ? atomicAdd(&a.bcur[i], c) : 0;
      sm.part.cnt[i] = 0;
    }
    __syncthreads();
    for (int e = e0 + t; e < e1; e += 256) {
      int s = a.ei[e];
      int d = a.ei[N_EDGES + e];
      int b = d >> 7;
      int r = atomicAdd(&sm.part.cnt[b], 1);
      a.pairs[sm.part.base[b] + r] = ((d & 127) << 17) | s;
    }
  }
  g.sync();

  // ---- P4: per-bucket degrees + offs + dinv + CSR scatter ----
  for (int b = blk; b < NB; b += grid) {
    int node0 = b << 7;
    int nloc = min(128, N_NODES - node0);
    int beg = a.bboff[b], end = a.bboff[b + 1];
    if (t < 128) sm.cd.ldeg[t] = 0;
    __syncthreads();
    for (int i = beg + t; i < end; i += 256)
      atomicAdd(&sm.cd.ldeg[(a.pairs[i] >> 17) & 127], 1);
    __syncthreads();
    int dv = (t < 128) ? sm.cd.ldeg[t] : 0;
    if (t < 128) sm.cd.sc[t] = dv;
    __syncthreads();
    for (int off = 1; off < 128; off <<= 1) {
      int u = (t >= off && t < 128) ? sm.cd.sc[t - off] : 0;
      __syncthreads();
      if (t < 128) sm.cd.sc[t] += u;
      __syncthreads();
    }
    if (t < nloc) {
      int o = beg + sm.cd.sc[t] - dv;
      a.offs[node0 + t] = o;
      sm.cd.lcur[t] = o;
      a.dinv[node0 + t] = rsqrtf((float)dv + 1.0f);
    }
    if (b == NB - 1 && t == 0) a.offs[N_NODES] = N_EDGES;
    __syncthreads();
    for (int i = beg + t; i < end; i += 256) {
      int p = a.pairs[i];
      int pos = atomicAdd(&sm.cd.lcur[(p >> 17) & 127], 1);
      a.csr[pos] = p & 131071;
    }
    __syncthreads();
  }
  g.sync();

  // ---- layer 1 ----
  for (int tile = blk; tile < NT64; tile += grid)
    d_gemm<HID, false, _Float16>(tile, a.bufA, a.W1H, a.W1L, nullptr, a.hw16);
  g.sync();
  for (int grp = blk; grp < NGROUP; grp += grid)
    d_agg<0>(grp, a.hw16, a.offs, a.csr, a.dinv, a.b1, a.bufA);
  g.sync();

  // ---- layer 2 ----
  for (int tile = blk; tile < NT64; tile += grid)
    d_gemm<HID, false, _Float16>(tile, a.bufA, a.W2H, a.W2L, nullptr, a.hw16);
  g.sync();
  for (int grp = blk; grp < NGROUP; grp += grid)
    d_agg<0>(grp, a.hw16, a.offs, a.csr, a.dinv, a.b2, a.bufA);
  g.sync();

  // ---- layer 3 (fused L2 normalize) ----
  for (int tile = blk; tile < NT64; tile += grid)
    d_gemm<HID, false, _Float16>(tile, a.bufA, a.W3H, a.W3L, nullptr, a.hw16);
  g.sync();
  for (int grp = blk; grp < NGROUP; grp += grid)
    d_agg<1>(grp, a.hw16, a.offs, a.csr, a.dinv, a.b3, a.out);
}

// ===================== fallback multi-kernel path (round-5 proven) =====================
__global__ __launch_bounds__(256) void f_prep(MegaArgs a) {
  int blk = blockIdx.x, t = threadIdx.x;
  if (blk < 32) d_split(a.Wp, a.WpH, a.WpL, IN_DIM, blk * 256 + t);
  else if (blk < 48) d_split(a.W1, a.W1H, a.W1L, HID, (blk - 32) * 256 + t);
  else if (blk < 64) d_split(a.W2, a.W2H, a.W2L, HID, (blk - 48) * 256 + t);
  else d_split(a.W3, a.W3H, a.W3L, HID, (blk - 64) * 256 + t);
}

__global__ __launch_bounds__(256) void f_bhist(MegaArgs a) {
  __shared__ int cnt[NB];
  int t = threadIdx.x;
  for (int i = t; i < NB; i += 256) cnt[i] = 0;
  __syncthreads();
  int e0 = blockIdx.x * 8192, e1 = min(e0 + 8192, N_EDGES);
  for (int e = e0 + t; e < e1; e += 256)
    atomicAdd(&cnt[a.ei[N_EDGES + e] >> 7], 1);
  __syncthreads();
  for (int i = t; i < NB; i += 256)
    if (cnt[i]) atomicAdd(&a.bsz[i], cnt[i]);
}

__global__ __launch_bounds__(256) void f_bscan(MegaArgs a) {
  __shared__ int sm[256];
  int t = threadIdx.x;
  int c[4];
  int idx0 = t * 4;
#pragma unroll
  for (int j = 0; j < 4; ++j) c[j] = (idx0 + j < NB) ? a.bsz[idx0 + j] : 0;
  int tsum = c[0] + c[1] + c[2] + c[3];
  int val = tsum;
  sm[t] = val;
  __syncthreads();
  for (int off = 1; off < 256; off <<= 1) {
    int u = (t >= off) ? sm[t - off] : 0;
    __syncthreads();
    val += u;
    sm[t] = val;
    __syncthreads();
  }
  int excl = val - tsum;
#pragma unroll
  for (int j = 0; j < 4; ++j) {
    int idx = idx0 + j;
    if (idx < NB) { a.bboff[idx] = excl; a.bcur[idx] = excl; }
    excl += c[j];
  }
  if (t == 255) a.bboff[NB] = val;
}

__global__ __launch_bounds__(256) void f_partition(MegaArgs a) {
  __shared__ int cnt[NB];
  __shared__ int base[NB];
  int t = threadIdx.x;
  for (int i = t; i < NB; i += 256) cnt[i] = 0;
  __syncthreads();
  int e0 = blockIdx.x * 8192, e1 = min(e0 + 8192, N_EDGES);
  for (int e = e0 + t; e < e1; e += 256)
    atomicAdd(&cnt[a.ei[N_EDGES + e] >> 7], 1);
  __syncthreads();
  for (int i = t; i < NB; i += 256) {
    int c = cnt[i];
    base[i] = c ? atomicAdd(&a.bcur[i], c) : 0;
    cnt[i] = 0;
  }
  __syncthreads();
  for (int e = e0 + t; e < e1; e += 256) {
    int s = a.ei[e];
    int d = a.ei[N_EDGES + e];
    int b = d >> 7;
    int r = atomicAdd(&cnt[b], 1);
    a.pairs[base[b] + r] = ((d & 127) << 17) | s;
  }
}

__global__ __launch_bounds__(256) void f_csrdeg(MegaArgs a) {
  __shared__ int ldeg[128];
  __shared__ int sc[128];
  __shared__ int lcur[128];
  int t = threadIdx.x;
  int b = blockIdx.x;
  int node0 = b << 7;
  int nloc = min(128, N_NODES - node0);
  int beg = a.bboff[b], end = a.bboff[b + 1];
  if (t < 128) ldeg[t] = 0;
  __syncthreads();
  for (int i = beg + t; i < end; i += 256)
    atomicAdd(&ldeg[(a.pairs[i] >> 17) & 127], 1);
  __syncthreads();
  int dv = (t < 128) ? ldeg[t] : 0;
  if (t < 128) sc[t] = dv;
  __syncthreads();
  for (int off = 1; off < 128; off <<= 1) {
    int u = (t >= off && t < 128) ? sc[t - off] : 0;
    __syncthreads();
    if (t < 128) sc[t] += u;
    __syncthreads();
  }
  if (t < nloc) {
    int o = beg + sc[t] - dv;
    a.offs[node0 + t] = o;
    lcur[t] = o;
    a.dinv[node0 + t] = rsqrtf((float)dv + 1.0f);
  }
  if (b == NB - 1 && t == 0) a.offs[N_NODES] = N_EDGES;
  __syncthreads();
  for (int i = beg + t; i < end; i += 256) {
    int p = a.pairs[i];
    int pos = atomicAdd(&lcur[(p >> 17) & 127], 1);
    a.csr[pos] = p & 131071;
  }
}

__global__ __launch_bounds__(256) void f_gemm_pre(MegaArgs a) {
  d_gemm<IN_DIM, true, float>(blockIdx.x, a.x, a.WpH, a.WpL, a.bp, a.bufA);
}

__global__ __launch_bounds__(256) void f_gemm64(MegaArgs a, const _Float16* Wh,
                                                const _Float16* Wl) {
  d_gemm<HID, false, _Float16>(blockIdx.x, a.bufA, Wh, Wl, nullptr, a.hw16);
}

__global__ __launch_bounds__(256) void f_agg_relu(MegaArgs a, const float* bias) {
  d_agg<0>(blockIdx.x, a.hw16, a.offs, a.csr, a.dinv, bias, a.bufA);
}

__global__ __launch_bounds__(256) void f_agg_norm(MegaArgs a) {
  d_agg<1>(blockIdx.x, a.hw16, a.offs, a.csr, a.dinv, a.b3, a.out);
}

extern "C" void kernel_launch(void* const* d_in, const int* in_sizes, int n_in,
                              void* d_out, int out_size, void* d_ws, size_t ws_size,
                              hipStream_t stream) {
  char* ws = (char*)d_ws;
  MegaArgs a;
  a.x  = (const float*)d_in[0];
  a.ei = (const int*)d_in[1];
  a.Wp = (const float*)d_in[2];  a.bp = (const float*)d_in[3];
  a.W1 = (const float*)d_in[4];  a.b1 = (const float*)d_in[5];
  a.W2 = (const float*)d_in[6];  a.b2 = (const float*)d_in[7];
  a.W3 = (const float*)d_in[8];  a.b3 = (const float*)d_in[9];
  a.out  = (float*)d_out;
  a.bufA = (float*)(ws + 0);                  // 25.6 MB
  a.hw16 = (_Float16*)(ws + 25600000);        // 12.8 MB
  a.pairs = (int*)(ws + 38400000);            // 6.4 MB (packed)
  a.csr   = (int*)(ws + 44800000);            // 6.4 MB
  a.offs  = (int*)(ws + 51200000);            // (N+1) ints
  a.dinv  = (float*)(ws + 51600016);          // 400 KB
  a.bsz   = (int*)(ws + 52000016);            // NB ints
  a.bboff = (int*)(ws + 52003152);            // NB+1 ints
  a.bcur  = (int*)(ws + 52006288);            // NB ints
  a.WpH = (_Float16*)(ws + 52009424);         // 16 KB
  a.WpL = (_Float16*)(ws + 52025808);
  a.W1H = (_Float16*)(ws + 52042192);         // 8 KB each
  a.W1L = (_Float16*)(ws + 52050384);
  a.W2H = (_Float16*)(ws + 52058576);
  a.W2L = (_Float16*)(ws + 52066768);
  a.W3H = (_Float16*)(ws + 52074960);
  a.W3L = (_Float16*)(ws + 52083152);

  // size the cooperative grid from the runtime's own occupancy computation
  int per_cu = 0;
  hipError_t qerr = hipOccupancyMaxActiveBlocksPerMultiprocessor(
      &per_cu, (const void*)k_mega, 256, 0);
  int grid = (qerr == hipSuccess) ? per_cu * 256 : 0;  // 256 CUs on MI355X
  if (grid > MAXGRID) grid = MAXGRID;

  hipError_t lerr = hipErrorUnknown;
  if (grid >= 256) {
    void* params[] = {(void*)&a};
    lerr = hipLaunchCooperativeKernel((const void*)k_mega, dim3(grid), dim3(256),
                                      params, 0, stream);
  }
  if (lerr != hipSuccess) {
    // fallback: proven multi-kernel pipeline
    (void)hipMemsetAsync(a.bsz, 0, NB * sizeof(int), stream);
    f_prep<<<80, 256, 0, stream>>>(a);
    f_bhist<<<196, 256, 0, stream>>>(a);
    f_bscan<<<1, 256, 0, stream>>>(a);
    f_partition<<<196, 256, 0, stream>>>(a);
    f_csrdeg<<<NB, 256, 0, stream>>>(a);
    f_gemm_pre<<<NT64, 256, 0, stream>>>(a);
    f_gemm64<<<NT64, 256, 0, stream>>>(a, a.W1H, a.W1L);
    f_agg_relu<<<NGROUP, 256, 0, stream>>>(a, a.b1);
    f_gemm64<<<NT64, 256, 0, stream>>>(a, a.W2H, a.W2L);
    f_agg_relu<<<NGROUP, 256, 0, stream>>>(a, a.b2);
    f_gemm64<<<NT64, 256, 0, stream>>>(a, a.W3H, a.W3L);
    f_agg_norm<<<NGROUP, 256, 0, stream>>>(a);
  }
}

// Round 8
// 382.509 us; speedup vs baseline: 2.9303x; 2.9303x over previous
//
#include <hip/hip_runtime.h>

#define N_NODES 100000
#define N_EDGES 1600000
#define IN_DIM 128
#define HID 64
#define NB 782               // ceil(100000 / 128) buckets of 128 nodes
#define NT64 1563            // ceil(N_NODES / 64) gemm tiles
#define NGROUP 25000         // N_NODES / 4 agg groups

typedef __attribute__((ext_vector_type(8))) _Float16 h8v;
typedef __attribute__((ext_vector_type(4))) float f4v;

struct Args {
  const float* x; const int* ei;
  const float* Wp; const float* bp;
  const float* W1; const float* b1;
  const float* W2; const float* b2;
  const float* W3; const float* b3;
  float* out;
  _Float16* bufA16; _Float16* hw16;
  int* pairs; int* csr; int* offs; float* dinv;
  int* bsz; int* bboff; int* bcur;
  _Float16* WpH; _Float16* WpL; _Float16* W1H; _Float16* W1L;
  _Float16* W2H; _Float16* W2L; _Float16* W3H; _Float16* W3L;
};

// ---------------- weight prep: split fp32 W[K][64] -> transposed half hi/lo ----
__device__ __forceinline__ void d_split(const float* __restrict__ W,
                                        _Float16* __restrict__ hi,
                                        _Float16* __restrict__ lo, int K, int i) {
  int k = i >> 6, n = i & 63;
  float v = W[i];
  _Float16 h = (_Float16)v;
  float r = v - (float)h;
  hi[n * K + k] = h;
  lo[n * K + k] = (_Float16)r;
}

__global__ __launch_bounds__(256) void f_prep(Args a) {
  int blk = blockIdx.x, t = threadIdx.x;
  if (blk < 32) d_split(a.Wp, a.WpH, a.WpL, IN_DIM, blk * 256 + t);
  else if (blk < 48) d_split(a.W1, a.W1H, a.W1L, HID, (blk - 32) * 256 + t);
  else if (blk < 64) d_split(a.W2, a.W2H, a.W2L, HID, (blk - 48) * 256 + t);
  else d_split(a.W3, a.W3H, a.W3L, HID, (blk - 64) * 256 + t);
}

// ---------------- bucket histogram ----------------
__global__ __launch_bounds__(256) void f_bhist(Args a) {
  __shared__ int cnt[NB];
  int t = threadIdx.x;
  for (int i = t; i < NB; i += 256) cnt[i] = 0;
  __syncthreads();
  int e0 = blockIdx.x * 8192, e1 = min(e0 + 8192, N_EDGES);
  for (int e = e0 + t; e < e1; e += 256)
    atomicAdd(&cnt[a.ei[N_EDGES + e] >> 7], 1);
  __syncthreads();
  for (int i = t; i < NB; i += 256)
    if (cnt[i]) atomicAdd(&a.bsz[i], cnt[i]);
}

// ---------------- bucket exclusive scan (1 block, 256 thr x 4 slots) ----------
__global__ __launch_bounds__(256) void f_bscan(Args a) {
  __shared__ int sm[256];
  int t = threadIdx.x;
  int c[4];
  int idx0 = t * 4;
#pragma unroll
  for (int j = 0; j < 4; ++j) c[j] = (idx0 + j < NB) ? a.bsz[idx0 + j] : 0;
  int tsum = c[0] + c[1] + c[2] + c[3];
  int val = tsum;
  sm[t] = val;
  __syncthreads();
  for (int off = 1; off < 256; off <<= 1) {
    int u = (t >= off) ? sm[t - off] : 0;
    __syncthreads();
    val += u;
    sm[t] = val;
    __syncthreads();
  }
  int excl = val - tsum;
#pragma unroll
  for (int j = 0; j < 4; ++j) {
    int idx = idx0 + j;
    if (idx < NB) { a.bboff[idx] = excl; a.bcur[idx] = excl; }
    excl += c[j];
  }
  if (t == 255) a.bboff[NB] = val;  // == N_EDGES
}

// ---------------- partition edges into buckets; pack (dlocal<<17 | src) --------
__global__ __launch_bounds__(256) void f_partition(Args a) {
  __shared__ int cnt[NB];
  __shared__ int base[NB];
  int t = threadIdx.x;
  for (int i = t; i < NB; i += 256) cnt[i] = 0;
  __syncthreads();
  int e0 = blockIdx.x * 8192, e1 = min(e0 + 8192, N_EDGES);
  for (int e = e0 + t; e < e1; e += 256)
    atomicAdd(&cnt[a.ei[N_EDGES + e] >> 7], 1);
  __syncthreads();
  for (int i = t; i < NB; i += 256) {
    int c = cnt[i];
    base[i] = c ? atomicAdd(&a.bcur[i], c) : 0;
    cnt[i] = 0;
  }
  __syncthreads();
  for (int e = e0 + t; e < e1; e += 256) {
    int s = a.ei[e];
    int d = a.ei[N_EDGES + e];
    int b = d >> 7;
    int r = atomicAdd(&cnt[b], 1);
    a.pairs[base[b] + r] = ((d & 127) << 17) | s;
  }
}

// ---------------- per-bucket degrees + offs + dinv + CSR scatter ---------------
__global__ __launch_bounds__(256) void f_csrdeg(Args a) {
  __shared__ int ldeg[128];
  __shared__ int sc[128];
  __shared__ int lcur[128];
  int t = threadIdx.x;
  int b = blockIdx.x;
  int node0 = b << 7;
  int nloc = min(128, N_NODES - node0);
  int beg = a.bboff[b], end = a.bboff[b + 1];
  if (t < 128) ldeg[t] = 0;
  __syncthreads();
  for (int i = beg + t; i < end; i += 256)
    atomicAdd(&ldeg[(a.pairs[i] >> 17) & 127], 1);
  __syncthreads();
  int dv = (t < 128) ? ldeg[t] : 0;
  if (t < 128) sc[t] = dv;
  __syncthreads();
  for (int off = 1; off < 128; off <<= 1) {
    int u = (t >= off && t < 128) ? sc[t - off] : 0;
    __syncthreads();
    if (t < 128) sc[t] += u;
    __syncthreads();
  }
  if (t < nloc) {
    int o = beg + sc[t] - dv;
    a.offs[node0 + t] = o;
    lcur[t] = o;
    a.dinv[node0 + t] = rsqrtf((float)dv + 1.0f);
  }
  if (b == NB - 1 && t == 0) a.offs[N_NODES] = N_EDGES;
  __syncthreads();
  for (int i = beg + t; i < end; i += 256) {
    int p = a.pairs[i];
    int pos = atomicAdd(&lcur[(p >> 17) & 127], 1);
    a.csr[pos] = p & 131071;
  }
}

// ---- pre GEMM: fp32 A (split into hi/lo), K=128, bias, out fp16 ----
__global__ __launch_bounds__(256) void f_gemm_pre(Args a) {
  const int K = IN_DIM;
  int wave = threadIdx.x >> 6;
  int lane = threadIdx.x & 63;
  int fi = lane & 15;
  int quad = lane >> 4;
  int r0 = blockIdx.x * 64 + wave * 16;
  int row_l = r0 + fi;
  if (row_l >= N_NODES) row_l = N_NODES - 1;
  const float* xp = a.x + (size_t)row_l * K + quad * 8;

  f4v acc[4];
#pragma unroll
  for (int ct = 0; ct < 4; ++ct) acc[ct] = (f4v){0.f, 0.f, 0.f, 0.f};

#pragma unroll
  for (int k0 = 0; k0 < K; k0 += 32) {
    f4v xa = *(const f4v*)(xp + k0);
    f4v xb = *(const f4v*)(xp + k0 + 4);
    h8v ah, al;
#pragma unroll
    for (int j = 0; j < 4; ++j) {
      _Float16 h = (_Float16)xa[j];
      ah[j] = h;
      al[j] = (_Float16)(xa[j] - (float)h);
    }
#pragma unroll
    for (int j = 0; j < 4; ++j) {
      _Float16 h = (_Float16)xb[j];
      ah[4 + j] = h;
      al[4 + j] = (_Float16)(xb[j] - (float)h);
    }
    const _Float16* whp = a.WpH + (size_t)fi * K + k0 + quad * 8;
    const _Float16* wlp = a.WpL + (size_t)fi * K + k0 + quad * 8;
#pragma unroll
    for (int ct = 0; ct < 4; ++ct) {
      h8v bh = *(const h8v*)(whp + (size_t)ct * 16 * K);
      h8v bl = *(const h8v*)(wlp + (size_t)ct * 16 * K);
      acc[ct] = __builtin_amdgcn_mfma_f32_16x16x32_f16(ah, bh, acc[ct], 0, 0, 0);
      acc[ct] = __builtin_amdgcn_mfma_f32_16x16x32_f16(al, bh, acc[ct], 0, 0, 0);
      acc[ct] = __builtin_amdgcn_mfma_f32_16x16x32_f16(ah, bl, acc[ct], 0, 0, 0);
    }
  }
#pragma unroll
  for (int ct = 0; ct < 4; ++ct) {
    float bv = a.bp[ct * 16 + fi];
#pragma unroll
    for (int j = 0; j < 4; ++j) {
      int orow = r0 + quad * 4 + j;
      if (orow < N_NODES)
        a.bufA16[(size_t)orow * HID + ct * 16 + fi] = (_Float16)(acc[ct][j] + bv);
    }
  }
}

// ---- hidden GEMM: fp16 A (exact), K=64, 2 MFMAs per tile-step, out fp16 ----
__global__ __launch_bounds__(256) void f_gemm64(Args a, const _Float16* __restrict__ Wh,
                                                const _Float16* __restrict__ Wl) {
  const int K = HID;
  int wave = threadIdx.x >> 6;
  int lane = threadIdx.x & 63;
  int fi = lane & 15;
  int quad = lane >> 4;
  int r0 = blockIdx.x * 64 + wave * 16;
  int row_l = r0 + fi;
  if (row_l >= N_NODES) row_l = N_NODES - 1;
  const _Float16* xp = a.bufA16 + (size_t)row_l * K + quad * 8;

  f4v acc[4];
#pragma unroll
  for (int ct = 0; ct < 4; ++ct) acc[ct] = (f4v){0.f, 0.f, 0.f, 0.f};

#pragma unroll
  for (int k0 = 0; k0 < K; k0 += 32) {
    h8v av = *(const h8v*)(xp + k0);   // exact fp16 A, no split
    const _Float16* whp = Wh + (size_t)fi * K + k0 + quad * 8;
    const _Float16* wlp = Wl + (size_t)fi * K + k0 + quad * 8;
#pragma unroll
    for (int ct = 0; ct < 4; ++ct) {
      h8v bh = *(const h8v*)(whp + (size_t)ct * 16 * K);
      h8v bl = *(const h8v*)(wlp + (size_t)ct * 16 * K);
      acc[ct] = __builtin_amdgcn_mfma_f32_16x16x32_f16(av, bh, acc[ct], 0, 0, 0);
      acc[ct] = __builtin_amdgcn_mfma_f32_16x16x32_f16(av, bl, acc[ct], 0, 0, 0);
    }
  }
#pragma unroll
  for (int ct = 0; ct < 4; ++ct) {
#pragma unroll
    for (int j = 0; j < 4; ++j) {
      int orow = r0 + quad * 4 + j;
      if (orow < N_NODES)
        a.hw16[(size_t)orow * HID + ct * 16 + fi] = (_Float16)acc[ct][j];
    }
  }
}

// ---- aggregation: wave per node, oct-parallel, 4-deep (32 gathers in flight) ----
// MODE 0: bias+relu -> fp16 bufA16    MODE 1: bias + L2 normalize -> fp32 out
template <int MODE>
__device__ __forceinline__ void d_agg(int grp, const _Float16* __restrict__ hw,
                                      const int* __restrict__ offs,
                                      const int* __restrict__ csr,
                                      const float* __restrict__ dinv,
                                      const float* __restrict__ bias,
                                      _Float16* __restrict__ out16,
                                      float* __restrict__ out32) {
  int node = grp * 4 + (threadIdx.x >> 6);
  int lane = threadIdx.x & 63;
  int oct = lane >> 3;
  int fi = lane & 7;
  float di = dinv[node];
  int beg = offs[node];
  int end = offs[node + 1];

  float acc[8];
#pragma unroll
  for (int c = 0; c < 8; ++c) acc[c] = 0.f;

  if (oct == 0) {  // self-loop term
    h8v hv = *(const h8v*)(hw + (size_t)node * HID + fi * 8);
    float w = di * di;
#pragma unroll
    for (int c = 0; c < 8; ++c) acc[c] += (float)hv[c] * w;
  }
  for (int e0 = beg + oct; e0 < end; e0 += 32) {
    int ss[4];
    float ww[4];
#pragma unroll
    for (int j = 0; j < 4; ++j) {
      int e = e0 + 8 * j;
      bool v = e < end;
      int s = csr[v ? e : beg];
      ss[j] = v ? s : node;
      ww[j] = v ? di : 0.0f;
    }
#pragma unroll
    for (int j = 0; j < 4; ++j) ww[j] *= dinv[ss[j]];
    h8v hv[4];
#pragma unroll
    for (int j = 0; j < 4; ++j)
      hv[j] = *(const h8v*)(hw + (size_t)ss[j] * HID + fi * 8);
#pragma unroll
    for (int j = 0; j < 4; ++j)
#pragma unroll
      for (int c = 0; c < 8; ++c) acc[c] += (float)hv[j][c] * ww[j];
  }
#pragma unroll
  for (int c = 0; c < 8; ++c) {
    float v = acc[c];
    v += __shfl_xor(v, 8);
    v += __shfl_xor(v, 16);
    v += __shfl_xor(v, 32);
    acc[c] = v;
  }
  if (oct == 0) {
#pragma unroll
    for (int c = 0; c < 8; ++c) acc[c] += bias[fi * 8 + c];
    if (MODE == 0) {
      h8v o;
#pragma unroll
      for (int c = 0; c < 8; ++c) o[c] = (_Float16)fmaxf(acc[c], 0.f);
      *(h8v*)(out16 + (size_t)node * HID + fi * 8) = o;
    } else {
      float ss = 0.f;
#pragma unroll
      for (int c = 0; c < 8; ++c) ss += acc[c] * acc[c];
      ss += __shfl_xor(ss, 1);
      ss += __shfl_xor(ss, 2);
      ss += __shfl_xor(ss, 4);
      float sc = 1.0f / fmaxf(sqrtf(ss), 1e-12f);
      f4v o0 = {acc[0] * sc, acc[1] * sc, acc[2] * sc, acc[3] * sc};
      f4v o1 = {acc[4] * sc, acc[5] * sc, acc[6] * sc, acc[7] * sc};
      *(f4v*)(out32 + (size_t)node * HID + fi * 8) = o0;
      *(f4v*)(out32 + (size_t)node * HID + fi * 8 + 4) = o1;
    }
  }
}

__global__ __launch_bounds__(256) void f_agg_relu(Args a, const float* bias) {
  d_agg<0>(blockIdx.x, a.hw16, a.offs, a.csr, a.dinv, bias, a.bufA16, nullptr);
}

__global__ __launch_bounds__(256) void f_agg_norm(Args a) {
  d_agg<1>(blockIdx.x, a.hw16, a.offs, a.csr, a.dinv, a.b3, nullptr, a.out);
}

extern "C" void kernel_launch(void* const* d_in, const int* in_sizes, int n_in,
                              void* d_out, int out_size, void* d_ws, size_t ws_size,
                              hipStream_t stream) {
  char* ws = (char*)d_ws;
  Args a;
  a.x  = (const float*)d_in[0];
  a.ei = (const int*)d_in[1];
  a.Wp = (const float*)d_in[2];  a.bp = (const float*)d_in[3];
  a.W1 = (const float*)d_in[4];  a.b1 = (const float*)d_in[5];
  a.W2 = (const float*)d_in[6];  a.b2 = (const float*)d_in[7];
  a.W3 = (const float*)d_in[8];  a.b3 = (const float*)d_in[9];
  a.out  = (float*)d_out;
  a.bufA16 = (_Float16*)(ws + 0);             // 12.8 MB fp16 activations
  a.hw16   = (_Float16*)(ws + 12800000);      // 12.8 MB fp16 gemm out
  a.pairs  = (int*)(ws + 25600000);           // 6.4 MB packed (dlocal<<17|src)
  a.csr    = (int*)(ws + 32000000);           // 6.4 MB
  a.offs   = (int*)(ws + 38400000);           // (N+1) ints
  a.dinv   = (float*)(ws + 38800016);         // 400 KB
  a.bsz    = (int*)(ws + 39200016);           // NB ints
  a.bboff  = (int*)(ws + 39203152);           // NB+1 ints
  a.bcur   = (int*)(ws + 39206288);           // NB ints
  a.WpH = (_Float16*)(ws + 39210000);         // 16 KB
  a.WpL = (_Float16*)(ws + 39226384);
  a.W1H = (_Float16*)(ws + 39242768);         // 8 KB each
  a.W1L = (_Float16*)(ws + 39250960);
  a.W2H = (_Float16*)(ws + 39259152);
  a.W2L = (_Float16*)(ws + 39267344);
  a.W3H = (_Float16*)(ws + 39275536);
  a.W3L = (_Float16*)(ws + 39283728);

  (void)hipMemsetAsync(a.bsz, 0, NB * sizeof(int), stream);
  f_prep<<<80, 256, 0, stream>>>(a);
  f_bhist<<<196, 256, 0, stream>>>(a);
  f_bscan<<<1, 256, 0, stream>>>(a);
  f_partition<<<196, 256, 0, stream>>>(a);
  f_csrdeg<<<NB, 256, 0, stream>>>(a);
  f_gemm_pre<<<NT64, 256, 0, stream>>>(a);
  f_gemm64<<<NT64, 256, 0, stream>>>(a, a.W1H, a.W1L);
  f_agg_relu<<<NGROUP, 256, 0, stream>>>(a, a.b1);
  f_gemm64<<<NT64, 256, 0, stream>>>(a, a.W2H, a.W2L);
  f_agg_relu<<<NGROUP, 256, 0, stream>>>(a, a.b2);
  f_gemm64<<<NT64, 256, 0, stream>>>(a, a.W3H, a.W3L);
  f_agg_norm<<<NGROUP, 256, 0, stream>>>(a);
}